// Round 11
// baseline (50.461 us; speedup 1.0000x reference)
//
#include <hip/hip_runtime.h>

#define B_ 8
#define C_ 256
#define K_ 19
#define N_ 16384              // H*W = 128*128
#define PIXBLK 512            // kernel A: 512 blocks x 256 thr x 1 px = B*N
#define BPB 64                // A-blocks per batch

typedef float nf4 __attribute__((ext_vector_type(4)));

// w with class id embedded in mantissa low 5 bits (relative err <= 3.7e-6).
__device__ __forceinline__ float embed(float w, int cls) {
    return __uint_as_float((__float_as_uint(w) & ~31u) | (unsigned)cls);
}
__device__ __forceinline__ int cls_of(float wc) {
    return (int)(__float_as_uint(wc) & 31u);
}

// ---- Kernel A: 1 px/thread. argmax -> wc = exp(s) with class embedded;
// ---- per-block partial denom via per-thread LDS columns (no atomics).
__global__ __launch_bounds__(256) void k_pix(
        const float* __restrict__ preds,
        float* __restrict__ wc_buf, float* __restrict__ pdenom) {
    __shared__ float pacc[K_ * 256];       // per-thread columns, race-free RMW
    int tid = threadIdx.x;
#pragma unroll
    for (int k = 0; k < K_; ++k) pacc[k * 256 + tid] = 0.0f;
    // no sync: each thread touches only column tid until the reduce

    int pix = blockIdx.x * 256 + tid;      // block covers 256 px, one batch
    int b   = pix >> 14;
    int n   = pix & (N_ - 1);
    const float* p = preds + (size_t)b * K_ * N_ + n;

    float best = p[0];
    int   bi   = 0;
#pragma unroll
    for (int k = 1; k < K_; ++k) {
        float v = p[(size_t)k * N_];
        if (v > best) { best = v; bi = k; }   // strict >: first max wins
    }
    // no max subtraction: logits ~N(0,1), exp(s) safe in f32; weight identical.
    float wc = embed(expf(best), bi);
    wc_buf[pix] = wc;
    pacc[bi * 256 + tid] += wc;            // plain RMW, column-private
    __syncthreads();

#pragma unroll
    for (int s = 128; s >= 1; s >>= 1) {
        for (int idx = tid; idx < K_ * s; idx += 256) {
            int k = idx / s, t = idx - k * s;
            pacc[k * 256 + t] += pacc[k * 256 + t + s];
        }
        __syncthreads();
    }
    if (tid < K_) pdenom[blockIdx.x * K_ + tid] = pacc[tid * 256];
}

// ---- Kernel B: one block per (b, channel-PAIR). Phase pipeline:
// ----   agg(c0)  ->  [scatter(c0) || agg(c1)]  ->  scatter(c1)
// ---- so HBM sees mixed read+write traffic (copy-rate) instead of
// ---- lockstep read-phase then write-phase across the whole grid.
__global__ __launch_bounds__(256) void k_agg_scatter(
        const float* __restrict__ x, const float* __restrict__ wc_buf,
        const float* __restrict__ pdenom, float* __restrict__ out) {
    __shared__ float acc[K_ * 256];        // 19456 B
    __shared__ float av[K_];
    int tid = threadIdx.x;
    int bid = blockIdx.x;                  // [0, 1024)
    int b    = bid >> 7;                   // 128 pairs per batch
    int c0   = (bid & 127) * 2;

    // per-lane denominator reciprocal (lanes 0..18 only, register-resident)
    float dinv = 0.0f;
    if (tid < K_) {
        float d = 0.0f;
        const float* pd = pdenom + (size_t)b * BPB * K_ + tid;
#pragma unroll
        for (int j = 0; j < BPB; ++j) d += pd[j * K_];   // L2-hot
        dinv = 1.0f / d;                   // empty segs -> inf -> nan, never gathered
    }

#pragma unroll
    for (int k = 0; k < K_; ++k) acc[k * 256 + tid] = 0.0f;
    // no sync: column tid is thread-private until the reduce

    const float4* wc4  = (const float4*)(wc_buf + (size_t)b * N_);
    const float4* x4_0 = (const float4*)(x + (size_t)(b * C_ + c0) * N_);
    const float4* x4_1 = x4_0 + N_ / 4;
    nf4* out4_0 = (nf4*)(out + (size_t)(b * C_ + c0) * N_);
    nf4* out4_1 = out4_0 + N_ / 4;

    // ---- phase 1: pure agg of c0 ----
#pragma unroll 4
    for (int i = tid; i < N_ / 4; i += 256) {
        float4 xv = x4_0[i];
        float4 wv = wc4[i];
        acc[cls_of(wv.x) * 256 + tid] += xv.x * wv.x;   // bank=tid%32, 2-way free
        acc[cls_of(wv.y) * 256 + tid] += xv.y * wv.y;
        acc[cls_of(wv.z) * 256 + tid] += xv.z * wv.z;
        acc[cls_of(wv.w) * 256 + tid] += xv.w * wv.w;
    }
    __syncthreads();
#pragma unroll
    for (int s = 128; s >= 1; s >>= 1) {               // index-parallel reduce
        for (int idx = tid; idx < K_ * s; idx += 256) {
            int k = idx / s, t = idx - k * s;
            acc[k * 256 + t] += acc[k * 256 + t + s];
        }
        __syncthreads();
    }
    if (tid < K_) av[tid] = acc[tid * 256] * dinv;
    __syncthreads();
#pragma unroll
    for (int k = 0; k < K_; ++k) acc[k * 256 + tid] = 0.0f;   // reinit, column-private
    // av is stable until the next reduce's final write -> safe to read in phase 2

    // ---- phase 2: scatter c0 (writes) interleaved with agg c1 (reads) ----
#pragma unroll 4
    for (int i = tid; i < N_ / 4; i += 256) {
        float4 xv = x4_1[i];
        float4 wv = wc4[i];                // L2-hot now
        int kx = cls_of(wv.x), ky = cls_of(wv.y), kz = cls_of(wv.z), kw = cls_of(wv.w);
        acc[kx * 256 + tid] += xv.x * wv.x;
        acc[ky * 256 + tid] += xv.y * wv.y;
        acc[kz * 256 + tid] += xv.z * wv.z;
        acc[kw * 256 + tid] += xv.w * wv.w;
        nf4 o = {av[kx], av[ky], av[kz], av[kw]};      // broadcast-ish LDS reads
        __builtin_nontemporal_store(o, &out4_0[i]);    // co-issued with x reads
    }
    __syncthreads();
#pragma unroll
    for (int s = 128; s >= 1; s >>= 1) {
        for (int idx = tid; idx < K_ * s; idx += 256) {
            int k = idx / s, t = idx - k * s;
            acc[k * 256 + t] += acc[k * 256 + t + s];
        }
        __syncthreads();
    }
    if (tid < K_) av[tid] = acc[tid * 256] * dinv;
    __syncthreads();

    // ---- phase 3: pure scatter of c1 ----
#pragma unroll 4
    for (int i = tid; i < N_ / 4; i += 256) {
        float4 wv = wc4[i];                // L2-hot
        nf4 o = {av[cls_of(wv.x)], av[cls_of(wv.y)],
                 av[cls_of(wv.z)], av[cls_of(wv.w)]};
        __builtin_nontemporal_store(o, &out4_1[i]);
    }
}

extern "C" void kernel_launch(void* const* d_in, const int* in_sizes, int n_in,
                              void* d_out, int out_size, void* d_ws, size_t ws_size,
                              hipStream_t stream) {
    const float* x     = (const float*)d_in[0];   // [B, C, H, W]
    const float* preds = (const float*)d_in[1];   // [B, K, H, W]
    float* out = (float*)d_out;                   // [B, C, H, W]

    char* ws = (char*)d_ws;
    float* wc_buf = (float*)(ws + 0);             // B*N f32 = 524288 B
    float* pdenom = (float*)(ws + 524288);        // 512*19 f32
    // all ws buffers fully overwritten every call -> poison-safe, no init dispatch

    hipLaunchKernelGGL(k_pix, dim3(PIXBLK), dim3(256), 0, stream,
                       preds, wc_buf, pdenom);
    hipLaunchKernelGGL(k_agg_scatter, dim3(B_ * C_ / 2), dim3(256), 0, stream,
                       x, wc_buf, pdenom, out);
}

// Round 12
// 49.504 us; speedup vs baseline: 1.0193x; 1.0193x over previous
//
#include <hip/hip_runtime.h>

#define B_ 8
#define C_ 256
#define N_ 16384              // H*W = 128*128
#define K_ 19
#define PIXBLK 256            // kernel A: 256 blocks x 256 thr x 2 px = B*N
#define BPB 32                // A-blocks per batch

typedef float nf4 __attribute__((ext_vector_type(4)));

// ---- Kernel A: 2 pixels/thread. argmax -> seg8, w=exp(s) -> w_buf;
// ---- per-block partial denom via per-thread LDS columns (no atomics).
__global__ __launch_bounds__(256) void k_pix(
        const float* __restrict__ preds,
        float* __restrict__ w_buf, unsigned char* __restrict__ seg8,
        float* __restrict__ pdenom) {
    __shared__ float pacc[K_ * 256];       // per-thread columns, race-free RMW
    int tid = threadIdx.x;
#pragma unroll
    for (int k = 0; k < K_; ++k) pacc[k * 256 + tid] = 0.0f;
    // no sync: each thread touches only column tid until the reduce

    int pix0 = (blockIdx.x * 256 + tid) * 2;   // block covers 512 px, one batch
    int b    = pix0 >> 14;
    int n    = pix0 & (N_ - 1);
    const float2* p2 = (const float2*)(preds + (size_t)b * K_ * N_ + n);

    float2 best = p2[0];
    int bx = 0, by = 0;
#pragma unroll
    for (int k = 1; k < K_; ++k) {
        float2 v = p2[(size_t)k * (N_ / 2)];
        if (v.x > best.x) { best.x = v.x; bx = k; }   // strict >: first max wins
        if (v.y > best.y) { best.y = v.y; by = k; }
    }
    // no max subtraction: logits ~N(0,1), exp(s) safe in f32; weight identical.
    float2 w2 = make_float2(expf(best.x), expf(best.y));
    ((float2*)w_buf)[pix0 / 2] = w2;
    uchar2 sv; sv.x = bx; sv.y = by;
    ((uchar2*)seg8)[pix0 / 2] = sv;

    pacc[bx * 256 + tid] += w2.x;          // plain RMW, column-private, in-order DS
    pacc[by * 256 + tid] += w2.y;
    __syncthreads();

#pragma unroll
    for (int s = 128; s >= 1; s >>= 1) {
        for (int idx = tid; idx < K_ * s; idx += 256) {
            int k = idx / s, t = idx - k * s;
            pacc[k * 256 + t] += pacc[k * 256 + t + s];
        }
        __syncthreads();
    }
    if (tid < K_) pdenom[blockIdx.x * K_ + tid] = pacc[tid * 256];
}

// ---- Kernel B: one block per (b,c). Stream x/w/seg, per-thread LDS-column
// ---- accumulation, index-parallel reduce, divide, nt-store scatter.
#define PROC(J)                                            \
    acc[S##J.x * 256 + tid] += X##J.x * W##J.x;            \
    acc[S##J.y * 256 + tid] += X##J.y * W##J.y;            \
    acc[S##J.z * 256 + tid] += X##J.z * W##J.z;            \
    acc[S##J.w * 256 + tid] += X##J.w * W##J.w;

__global__ __launch_bounds__(256) void k_agg_scatter(
        const float* __restrict__ x, const float* __restrict__ w_buf,
        const unsigned char* __restrict__ seg8, const float* __restrict__ pdenom,
        float* __restrict__ out) {
    __shared__ float acc[K_ * 256];        // 19456 B -> 8 blocks/CU (160KB exactly)
    __shared__ float av[K_];
    int tid = threadIdx.x;
    int b = blockIdx.x >> 8;               // C = 256
    int c = blockIdx.x & 255;

#pragma unroll
    for (int k = 0; k < K_; ++k) acc[k * 256 + tid] = 0.0f;
    // no sync: column tid is thread-private until the reduce

    const float4* x4 = (const float4*)(x + (size_t)(b * C_ + c) * N_);
    const float4* w4 = (const float4*)(w_buf + (size_t)b * N_);
    const uchar4* s4 = (const uchar4*)(seg8 + (size_t)b * N_);

    // 16 groups of float4 per thread; process 2 per step, prefetch next 2.
    float4 X0 = x4[tid],       W0 = w4[tid];       uchar4 S0 = s4[tid];
    float4 X1 = x4[tid + 256], W1 = w4[tid + 256]; uchar4 S1 = s4[tid + 256];
#pragma unroll
    for (int m = 1; m < 8; ++m) {
        int idx = tid + m * 512;
        float4 TX0 = x4[idx],       TW0 = w4[idx];       uchar4 TS0 = s4[idx];
        float4 TX1 = x4[idx + 256], TW1 = w4[idx + 256]; uchar4 TS1 = s4[idx + 256];
        PROC(0) PROC(1)                    // consume previous groups
        X0 = TX0; W0 = TW0; S0 = TS0;
        X1 = TX1; W1 = TW1; S1 = TS1;
    }
    PROC(0) PROC(1)                        // final two groups
    __syncthreads();

    // index-parallel tree reduce: all 256 threads busy on K_*s items per step
#pragma unroll
    for (int s = 128; s >= 1; s >>= 1) {
        for (int idx = tid; idx < K_ * s; idx += 256) {
            int k = idx / s, t = idx - k * s;
            acc[k * 256 + t] += acc[k * 256 + t + s];
        }
        __syncthreads();
    }

    if (tid < K_) {
        float d = 0.0f;
        const float* pd = pdenom + (size_t)b * BPB * K_ + tid;
#pragma unroll
        for (int j = 0; j < BPB; ++j) d += pd[j * K_];   // L2-hot
        av[tid] = acc[tid * 256] / d;      // empty segs -> nan, never gathered
    }
    __syncthreads();

    nf4* out4 = (nf4*)(out + (size_t)(b * C_ + c) * N_);
    for (int i = tid; i < N_ / 4; i += 256) {
        uchar4 sv = s4[i];                 // L2-hot (16 KB/batch)
        nf4 o = {av[sv.x], av[sv.y], av[sv.z], av[sv.w]};
        __builtin_nontemporal_store(o, &out4[i]);
    }
}

extern "C" void kernel_launch(void* const* d_in, const int* in_sizes, int n_in,
                              void* d_out, int out_size, void* d_ws, size_t ws_size,
                              hipStream_t stream) {
    const float* x     = (const float*)d_in[0];   // [B, C, H, W]
    const float* preds = (const float*)d_in[1];   // [B, K, H, W]
    float* out = (float*)d_out;                   // [B, C, H, W]

    char* ws = (char*)d_ws;
    float*         w_buf  = (float*)(ws + 0);              // B*N f32 = 524288 B
    unsigned char* seg8   = (unsigned char*)(ws + 524288); // B*N u8  = 131072 B
    float*         pdenom = (float*)(ws + 655360);         // 256*19 f32
    // all ws buffers fully overwritten every call -> poison-safe, no init dispatch

    hipLaunchKernelGGL(k_pix, dim3(PIXBLK), dim3(256), 0, stream,
                       preds, w_buf, seg8, pdenom);
    hipLaunchKernelGGL(k_agg_scatter, dim3(B_ * C_), dim3(256), 0, stream,
                       x, w_buf, seg8, pdenom, out);
}